// Round 25
// baseline (154.865 us; speedup 1.0000x reference)
//
#include <hip/hip_runtime.h>
#include <stdint.h>

// HamiltonianFlow: x [256, 8, 32, 2] (q,p); H = 0.5*sum(p^2) + MLP(q).
// dq/dt = p, dp/dt = -W u(z), z = W^T q + b1, u = (1-tanh^2(z)).*W2.
// 100 RK4 steps, z-space iteration with M = W^T W (R15-R24 verified):
//   z2 = z1+hdt*P; z3 = z1+hdt*P-hdt^2*Y1^; z4 = z1+dt*P-dt*hdt*Y2^
//   (Y^ = previous step's, R23-verified lag: dz ~ 2.5e-7, 100x below the
//   f16 u-rounding already dominating absmax)
//   z1' = z1+dt*P-dt*dt6*(Y1+Y2+Y3);  P' = P-dt6*(Y1+2Y2+2Y3+Y4) [exact Ys]
// 4 u-vectors packed in A rows m%4={0,1,2,3}; ONE MFMA block/step gives
// Y1..Y4 in-lane (C[0..3]). Double-buffered ubuf -> ONE barrier/step (R24).
//
// R25: 4 WAVES x 4 TILES on the R24 single-barrier structure. R24 decomp
// (~1870 cyc/step): LDS 64 b128/CU ~= 768, barrier ~= 408 (measured via
// R23->R24 delta: 17us/100 barriers), MFMA issue 515, VALU ~330. A-reads
// scale with wave count (unique data just 2 KB/step); halving waves halves
// LDS (384) and barrier (~250) at unchanged MFMA issue/SIMD. (R20's 4x4
// regression was on the old 2-phase structure with 4 barriers + redundant
// VALU -- costs that no longer exist.) Wave w owns tiles 4w..4w+3, comps
// ci = 64w+16i+s; quad handles stage quad+1 for all 4 comps (4 exp/lane,
// 8 indep chains ILP). 1 wave/SIMD: 512-reg budget, wM[4][8]=128 AGPR-
// direct ("a" constraint), no spill.
// ubuf stride US=272 f16 (544 B == 32 mod 128: 4 vector rows on 4 bank
// quarters, residual 2-way free). Transposed W^T staging (contiguous b128
// wF/aM). M-build scr stride 20. Reconstruction (R15): sp=u1+2u2+2u3+u4,
// sq=u1+u2+u3; S1=sum sp_n, S23=sum (99-n)sp_n+sq_n;
// p_T = p0-dt6*W*S1, q_T = q0+dt*100*p0-dt*dt6*W*S23.
// FULL unroll on every reg-array access (R4: dynamic index => scratch).
// Numerics: f16 storage (W, M, u, S), fp32 MFMA accum + fp32 z1/P state.

typedef _Float16 v8h __attribute__((ext_vector_type(8)));
typedef float v4f __attribute__((ext_vector_type(4)));

#define NSTEPS 100
#define WS 264    // wldsT row stride (f16): row = one W-COLUMN, 16B-aligned
#define US 272    // ubuf row stride, f16 (544 B == 32 mod 128: 4-way split)

// D(+=C) in VGPRs, A (packed-vector frag) in VGPRs, B (M-frag) from AGPRs.
#define MFMA_AV(C, A, B) \
    asm("v_mfma_f32_16x16x32_f16 %0, %1, %2, %0" : "+v"(C) : "v"(A), "a"(B))

__global__ __launch_bounds__(256, 1)
void ham_kernel(const float* __restrict__ x0, const float* __restrict__ W1,
                const float* __restrict__ b1, const float* __restrict__ W2,
                float* __restrict__ out)
{
    __shared__ __align__(16)  _Float16 wldsT[256 * WS];  // 135168 B: W^T (f16)
    __shared__ __align__(16)  float    mscr[16 * 320];   // 20480 B: M scratch
    __shared__ __align__(128) _Float16 ubuf[8 * US];     // 4352 B: 2 x 4 rows

    const int t = threadIdx.x;
    const int w = t >> 6;          // wave 0..3: owns tiles 4w..4w+3
    const int l = t & 63;
    const int quad = l >> 4;       // K-subgroup / stage slot (stage quad+1)
    const int s = l & 15;          // owned column / A-row
    const int blk = blockIdx.x;
    const int sel = (s & 3) * US;  // A-row m%4 = r -> vector r
    const int cb = 64 * w + s;     // comp i: cb + 16*i

    // ---- stage W^T -> LDS f16: wldsT[c][r] = W[r][c] ----
    {
        const int c = t;
        #pragma unroll 1
        for (int r0 = 0; r0 < 256; r0 += 8) {
            v8h h;
            #pragma unroll
            for (int j = 0; j < 8; ++j)
                h[j] = (_Float16)W1[(r0 + j) * 256 + c];
            *(v8h*)(wldsT + c * WS + r0) = h;   // b128, one-time
        }
    }
    __syncthreads();

    // ---- wF: own-column W^T frags (B-op), 4 tiles, contiguous b128 ----
    v8h wF[4][8];
    #pragma unroll
    for (int i = 0; i < 4; ++i)
        #pragma unroll
        for (int kk = 0; kk < 8; ++kk)
            wF[i][kk] = *(const v8h*)(wldsT + (cb + 16 * i) * WS
                                             + 32 * kk + 8 * quad);

    // ---- build M = W^T W col-block frags wM[i] (B-op: M[k][ci]) ----
    v8h wM[4][8];
    float* scr = mscr + (w * 4) * 320;
    #pragma unroll
    for (int kb = 0; kb < 16; ++kb) {
        v8h aM[8];   // A[m=s][k=8quad+j] = wldsT[(16kb+s)*WS + 32kk+8quad+j]
        #pragma unroll
        for (int kk = 0; kk < 8; ++kk)
            aM[kk] = *(const v8h*)(wldsT + (16 * kb + s) * WS
                                          + 32 * kk + 8 * quad);
        v4f D0 = {0.f,0.f,0.f,0.f}, D1 = {0.f,0.f,0.f,0.f};
        v4f D2 = {0.f,0.f,0.f,0.f}, D3 = {0.f,0.f,0.f,0.f};
        #pragma unroll
        for (int kk = 0; kk < 8; ++kk) {
            D0 = __builtin_amdgcn_mfma_f32_16x16x32_f16(aM[kk], wF[0][kk], D0, 0, 0, 0);
            D1 = __builtin_amdgcn_mfma_f32_16x16x32_f16(aM[kk], wF[1][kk], D1, 0, 0, 0);
            D2 = __builtin_amdgcn_mfma_f32_16x16x32_f16(aM[kk], wF[2][kk], D2, 0, 0, 0);
            D3 = __builtin_amdgcn_mfma_f32_16x16x32_f16(aM[kk], wF[3][kk], D3, 0, 0, 0);
        }
        *(v4f*)(scr + 0 * 320 + s * 20 + 4 * quad) = D0;
        *(v4f*)(scr + 1 * 320 + s * 20 + 4 * quad) = D1;
        *(v4f*)(scr + 2 * 320 + s * 20 + 4 * quad) = D2;
        *(v4f*)(scr + 3 * 320 + s * 20 + 4 * quad) = D3;
        asm volatile("s_waitcnt lgkmcnt(0)" ::: "memory");  // in-wave x-lane
        if ((quad >> 1) == (kb & 1)) {
            #pragma unroll
            for (int j = 0; j < 8; ++j) {
                wM[0][kb >> 1][j] = (_Float16)scr[0 * 320 + s * 20 + 8 * (quad & 1) + j];
                wM[1][kb >> 1][j] = (_Float16)scr[1 * 320 + s * 20 + 8 * (quad & 1) + j];
                wM[2][kb >> 1][j] = (_Float16)scr[2 * 320 + s * 20 + 8 * (quad & 1) + j];
                wM[3][kb >> 1][j] = (_Float16)scr[3 * 320 + s * 20 + 8 * (quad & 1) + j];
            }
        }
        asm volatile("s_waitcnt lgkmcnt(0)" ::: "memory");
    }

    float b1r[4], w2r[4], q0o[4], p0o[4];
    #pragma unroll
    for (int i = 0; i < 4; ++i) {
        const int ci = cb + 16 * i;
        b1r[i] = b1[ci];
        w2r[i] = W2[ci];
        float2 qp = ((const float2*)(x0 + (size_t)blk * 512))[ci];
        q0o[i] = qp.x; p0o[i] = qp.y;
        if (quad == 0) {
            ubuf[ci] = (_Float16)qp.x;
            ubuf[US + ci] = (_Float16)qp.y;
            ubuf[2 * US + ci] = (_Float16)0.f;
            ubuf[3 * US + ci] = (_Float16)0.f;
        }
    }
    __syncthreads();

    // ---- prologue: buf0 rows {q0,p0,0,0} -> z1 = C[0]+b1, P = C[1] ----
    float z1[4], P[4];
    {
        const _Float16* ab = ubuf + sel + 8 * quad;
        v8h a[8];
        #pragma unroll
        for (int kk = 0; kk < 8; ++kk)
            a[kk] = *(const v8h*)(ab + 32 * kk);
        v4f C[4];
        #pragma unroll
        for (int i = 0; i < 4; ++i) C[i] = (v4f){0.f,0.f,0.f,0.f};
        #pragma unroll
        for (int kk = 0; kk < 8; ++kk)
            #pragma unroll
            for (int i = 0; i < 4; ++i)
                C[i] = __builtin_amdgcn_mfma_f32_16x16x32_f16(
                           a[kk], wF[i][kk], C[i], 0, 0, 0);
        #pragma unroll
        for (int i = 0; i < 4; ++i) {
            z1[i] = C[i][0] + b1r[i];
            P[i]  = C[i][1];
        }
    }
    __syncthreads();   // prologue reads done before iter-0 overwrites buf0

    const float dt = 0.01f, hdt = 0.005f, dt6 = 0.01f / 6.f;
    const float dtdt6 = dt * dt6, hdt2 = hdt * hdt, dthdt = dt * hdt;
    // quad's stage: aq (P coeff), bq (lagged-Y coeff); stage weights
    const float aq  = (quad == 0) ? 0.f : (quad == 3) ? dt : hdt;
    const float bq  = (quad == 2) ? hdt2 : (quad == 3) ? dthdt : 0.f;
    const float wsp = (quad == 0 || quad == 3) ? 1.f : 2.f;
    const float wsq = (quad == 3) ? 0.f : 1.f;

    float hY[4] = {0.f, 0.f, 0.f, 0.f};   // quad2 lags Y1, quad3 lags Y2
    float S1p[4] = {0.f,0.f,0.f,0.f}, S23p[4] = {0.f,0.f,0.f,0.f};
    float cn = 99.f;

    #pragma unroll 1
    for (int n = 0; n < NSTEPS; ++n) {
        const int bo = (n & 1) * (4 * US);   // double-buffer offset

        // ---- quad-assigned stage z (4 comps), lagged Y in bq term ----
        float u[4];
        #pragma unroll
        for (int i = 0; i < 4; ++i) {
            float zA = z1[i] + aq * P[i] - bq * hY[i];
            float e = __expf(2.f * zA);
            float hh = 1.f - 2.f / (e + 1.f);
            u[i] = (1.f - hh * hh) * w2r[i];
            ubuf[bo + quad * US + cb + 16 * i] = (_Float16)u[i];  // full exec
        }
        __syncthreads();   // the ONLY barrier per step

        // ---- ONE MFMA block: Y1..Y4 for 4 comps, all in-lane ----
        float Y1[4], Y2[4], Y3[4], Y4[4];
        {
            const _Float16* ab = ubuf + bo + sel + 8 * quad;
            v8h a[8];
            #pragma unroll
            for (int kk = 0; kk < 8; ++kk)
                a[kk] = *(const v8h*)(ab + 32 * kk);
            v4f Ca[4], Cb[4];
            #pragma unroll
            for (int i = 0; i < 4; ++i) { Ca[i] = (v4f){0.f,0.f,0.f,0.f}; Cb[i] = Ca[i]; }
            #pragma unroll
            for (int kk = 0; kk < 8; kk += 2)
                #pragma unroll
                for (int i = 0; i < 4; ++i) {
                    MFMA_AV(Ca[i], a[kk], wM[i][kk]);
                    MFMA_AV(Cb[i], a[kk + 1], wM[i][kk + 1]);
                }
            #pragma unroll
            for (int i = 0; i < 4; ++i) {
                v4f Cs = Ca[i] + Cb[i];
                Y1[i] = Cs[0]; Y2[i] = Cs[1]; Y3[i] = Cs[2]; Y4[i] = Cs[3];
            }
        }
        // no second barrier: next iter writes the OTHER buffer (R24 proof).

        // ---- step update (exact current Ys); refresh lagged Y ----
        #pragma unroll
        for (int i = 0; i < 4; ++i) {
            z1[i] = z1[i] + dt * P[i] - dtdt6 * (Y1[i] + Y2[i] + Y3[i]);
            P[i]  = P[i] - dt6 * (Y1[i] + 2.f * Y2[i] + 2.f * Y3[i] + Y4[i]);
            hY[i] = (quad == 3) ? Y2[i] : Y1[i];
            S1p[i] += wsp * u[i];
            S23p[i] += cn * (wsp * u[i]) + wsq * u[i];
        }
        cn -= 1.f;
    }

    // ---- epilogue: reduce S over quads; buf0 rows {S1, S23, 0, 0} ----
    #pragma unroll
    for (int i = 0; i < 4; ++i) {
        S1p[i]  += __shfl_xor(S1p[i], 16, 64);
        S1p[i]  += __shfl_xor(S1p[i], 32, 64);
        S23p[i] += __shfl_xor(S23p[i], 16, 64);
        S23p[i] += __shfl_xor(S23p[i], 32, 64);
    }
    __syncthreads();
    #pragma unroll
    for (int i = 0; i < 4; ++i)
        if (quad == 0) {
            ubuf[cb + 16 * i] = (_Float16)S1p[i];
            ubuf[US + cb + 16 * i] = (_Float16)S23p[i];
            ubuf[2 * US + cb + 16 * i] = (_Float16)0.f;
            ubuf[3 * US + cb + 16 * i] = (_Float16)0.f;
        }
    __syncthreads();
    // wBt[i][kk][j] = W[ci][32kk+8quad+j] = wldsT[(32kk+8quad+j)*WS + ci]
    v8h wBt[4][8];
    #pragma unroll
    for (int i = 0; i < 4; ++i)
        #pragma unroll
        for (int kk = 0; kk < 8; ++kk)
            #pragma unroll
            for (int j = 0; j < 8; ++j)
                wBt[i][kk][j] = wldsT[(32 * kk + 8 * quad + j) * WS + cb + 16 * i];
    {
        const _Float16* ab = ubuf + sel + 8 * quad;
        v8h a[8];
        #pragma unroll
        for (int kk = 0; kk < 8; ++kk)
            a[kk] = *(const v8h*)(ab + 32 * kk);
        v4f C[4];
        #pragma unroll
        for (int i = 0; i < 4; ++i) C[i] = (v4f){0.f,0.f,0.f,0.f};
        #pragma unroll
        for (int kk = 0; kk < 8; ++kk)
            #pragma unroll
            for (int i = 0; i < 4; ++i)
                C[i] = __builtin_amdgcn_mfma_f32_16x16x32_f16(
                           a[kk], wBt[i][kk], C[i], 0, 0, 0);
        const float dt6e = 0.01f / 6.f, dtdt6e = 0.01f * dt6e;
        #pragma unroll
        for (int i = 0; i < 4; ++i) {
            float pT = p0o[i] - dt6e * C[i][0];
            float qT = q0o[i] + 0.01f * (float)NSTEPS * p0o[i] - dtdt6e * C[i][1];
            if (quad == 0)
                ((float2*)(out + (size_t)blk * 512))[cb + 16 * i] =
                    make_float2(qT, pT);
        }
    }
}

extern "C" void kernel_launch(void* const* d_in, const int* in_sizes, int n_in,
                              void* d_out, int out_size, void* d_ws, size_t ws_size,
                              hipStream_t stream) {
    const float* x0 = (const float*)d_in[0];
    const float* W1 = (const float*)d_in[1];
    const float* b1 = (const float*)d_in[2];
    const float* W2 = (const float*)d_in[3];
    // d_in[4] = b2: constant offset, no effect on the gradient/dynamics.
    float* out = (float*)d_out;
    hipLaunchKernelGGL(ham_kernel, dim3(256), dim3(256), 0, stream,
                       x0, W1, b1, W2, out);
}

// Round 26
// 138.553 us; speedup vs baseline: 1.1177x; 1.1177x over previous
//
#include <hip/hip_runtime.h>
#include <stdint.h>

// HamiltonianFlow: x [256, 8, 32, 2] (q,p); H = 0.5*sum(p^2) + MLP(q).
// dq/dt = p, dp/dt = -W u(z), z = W^T q + b1, u = (1-tanh^2(z)).*W2.
// 100 RK4 steps, z-space iteration with M = W^T W (R15-R24 verified):
//   z2 = z1+hdt*P; z3 = z1+hdt*P-hdt^2*Y1^; z4 = z1+dt*P-dt*hdt*Y2^
//   (Y^ = previous step's, R23-verified lag: dz ~ 2.5e-7, 100x below the
//   f16 u-rounding already dominating absmax)
//   z1' = z1+dt*P-dt*dt6*(Y1+Y2+Y3);  P' = P-dt6*(Y1+2Y2+2Y3+Y4) [exact Ys]
// 4 u-vectors packed in A rows m%4={0,1,2,3}; ONE MFMA block/step gives
// Y1..Y4 in-lane (C[0..3]). Double-buffered ubuf -> ONE barrier/step.
//
// R26 = R24 VERBATIM (the measured optimum: steady 90us). R25 (4 waves x
// 4 tiles) regressed to 110us steady -- third confirmation (R14, R20, R25)
// that 1 wave/SIMD exposes the post-barrier serial chain (ds_read latency
// -> MFMA drain -> exp); 2 waves/SIMD co-issue covers it. 8 waves x 2
// tiles is the genuine optimum: A-frag addresses depend only on (quad,s),
// so LDS duplication is wave-count-bound, and register files can't be
// shared cross-wave. Remaining wall (1870 cyc/step): barrier ~408
// (measured R23->R24), LDS pipe 64 b128 ~768, latency/VALU tail ~700;
// algorithmic floor of this lockstep family ~71us.
// ubuf stride US=272 f16 (544 B == 32 mod 128: 4 vector rows on 4 bank
// quarters, residual 2-way aliasing free). Quad-split nonlinearity (R22):
// quad q computes stage q+1 for both comps; weights wsp={1,2,2,1},
// wsq={1,1,1,0}; S partials reduced by shfl_xor(16)+shfl_xor(32).
// Transposed W^T staging (contiguous b128 wF/aM), AGPR-direct wM ("a"),
// M-build scr stride 20. Reconstruction (R15): sp=u1+2u2+2u3+u4,
// sq=u1+u2+u3; S1=sum sp_n, S23=sum (99-n)sp_n+sq_n;
// p_T = p0-dt6*W*S1, q_T = q0+dt*100*p0-dt*dt6*W*S23.
// FULL unroll on every reg-array access (R4: dynamic index => scratch).
// Numerics: f16 storage (W, M, u, S), fp32 MFMA accum + fp32 z1/P state.

typedef _Float16 v8h __attribute__((ext_vector_type(8)));
typedef float v4f __attribute__((ext_vector_type(4)));

#define NSTEPS 100
#define WS 264    // wldsT row stride (f16): row = one W-COLUMN, 16B-aligned
#define US 272    // ubuf row stride, f16 (544 B == 32 mod 128: 4-way split)

// D(+=C) in VGPRs, A (packed-vector frag) in VGPRs, B (M-frag) from AGPRs.
#define MFMA_AV(C, A, B) \
    asm("v_mfma_f32_16x16x32_f16 %0, %1, %2, %0" : "+v"(C) : "v"(A), "a"(B))

__global__ __launch_bounds__(512, 2)
void ham_kernel(const float* __restrict__ x0, const float* __restrict__ W1,
                const float* __restrict__ b1, const float* __restrict__ W2,
                float* __restrict__ out)
{
    __shared__ __align__(16)  _Float16 wldsT[256 * WS];  // 135168 B: W^T (f16)
    __shared__ __align__(16)  float    mscr[8 * 640];    // 20480 B: M scratch
    __shared__ __align__(128) _Float16 ubuf[8 * US];     // 4352 B: 2 x 4 rows

    const int t = threadIdx.x;
    const int w = t >> 6;          // wave 0..7: owns tiles {2w, 2w+1}
    const int l = t & 63;
    const int quad = l >> 4;       // K-subgroup / stage slot (stage quad+1)
    const int s = l & 15;          // owned column / A-row
    const int c0 = 32 * w + s;          // comp, tile 2w
    const int c1 = 32 * w + 16 + s;     // comp, tile 2w+1
    const int blk = blockIdx.x;
    const int sel = (s & 3) * US;  // A-row m%4 = r -> vector r

    // ---- stage W^T -> LDS f16: wldsT[c][r] = W[r][c] ----
    {
        const int c = t & 255;
        const int rbase = (t >> 8) * 128;
        #pragma unroll 1
        for (int r0 = 0; r0 < 128; r0 += 8) {
            v8h h;
            #pragma unroll
            for (int j = 0; j < 8; ++j)
                h[j] = (_Float16)W1[(rbase + r0 + j) * 256 + c];
            *(v8h*)(wldsT + c * WS + rbase + r0) = h;   // b128, one-time
        }
    }
    __syncthreads();

    // ---- wF: own-column W^T frags (B-op), contiguous b128 from wldsT ----
    v8h wF0[8], wF1[8];
    #pragma unroll
    for (int kk = 0; kk < 8; ++kk) {
        wF0[kk] = *(const v8h*)(wldsT + c0 * WS + 32 * kk + 8 * quad);
        wF1[kk] = *(const v8h*)(wldsT + c1 * WS + 32 * kk + 8 * quad);
    }

    // ---- build M = W^T W column-block frags wM0/wM1 (B-op: M[k][c]) ----
    v8h wM0[8], wM1[8];
    float* scr0 = mscr + w * 640;
    float* scr1 = scr0 + 320;
    #pragma unroll
    for (int kb = 0; kb < 16; ++kb) {
        v8h aM[8];   // A[m=s][k=8quad+j] = wldsT[(16kb+s)*WS + 32kk+8quad+j]
        #pragma unroll
        for (int kk = 0; kk < 8; ++kk)
            aM[kk] = *(const v8h*)(wldsT + (16 * kb + s) * WS
                                          + 32 * kk + 8 * quad);
        v4f D0 = {0.f,0.f,0.f,0.f}, D1 = {0.f,0.f,0.f,0.f};
        #pragma unroll
        for (int kk = 0; kk < 8; ++kk) {
            D0 = __builtin_amdgcn_mfma_f32_16x16x32_f16(aM[kk], wF0[kk], D0, 0, 0, 0);
            D1 = __builtin_amdgcn_mfma_f32_16x16x32_f16(aM[kk], wF1[kk], D1, 0, 0, 0);
        }
        *(v4f*)(scr0 + s * 20 + 4 * quad) = D0;
        *(v4f*)(scr1 + s * 20 + 4 * quad) = D1;
        asm volatile("s_waitcnt lgkmcnt(0)" ::: "memory");  // in-wave x-lane
        if ((quad >> 1) == (kb & 1)) {
            #pragma unroll
            for (int j = 0; j < 8; ++j) {
                wM0[kb >> 1][j] = (_Float16)scr0[s * 20 + 8 * (quad & 1) + j];
                wM1[kb >> 1][j] = (_Float16)scr1[s * 20 + 8 * (quad & 1) + j];
            }
        }
        asm volatile("s_waitcnt lgkmcnt(0)" ::: "memory");
    }

    const float b1r0 = b1[c0], b1r1 = b1[c1];
    const float w2r0 = W2[c0], w2r1 = W2[c1];
    float2 qp0 = ((const float2*)(x0 + (size_t)blk * 512))[c0];
    float2 qp1 = ((const float2*)(x0 + (size_t)blk * 512))[c1];
    const float q0o0 = qp0.x, p0o0 = qp0.y;
    const float q0o1 = qp1.x, p0o1 = qp1.y;

    // ---- prologue: buf0 rows {q0, p0, 0, 0} -> z1 (C[0]), P (C[1]) ----
    if (quad == 0) {
        ubuf[c0] = (_Float16)q0o0;  ubuf[c1] = (_Float16)q0o1;
        ubuf[US + c0] = (_Float16)p0o0;  ubuf[US + c1] = (_Float16)p0o1;
        ubuf[2 * US + c0] = (_Float16)0.f;  ubuf[2 * US + c1] = (_Float16)0.f;
        ubuf[3 * US + c0] = (_Float16)0.f;  ubuf[3 * US + c1] = (_Float16)0.f;
    }
    __syncthreads();
    float z10, P0, z11, P1;
    {
        const _Float16* ab = ubuf + sel + 8 * quad;
        v4f C0a = {0.f,0.f,0.f,0.f}, C0b = {0.f,0.f,0.f,0.f};
        v4f C1a = {0.f,0.f,0.f,0.f}, C1b = {0.f,0.f,0.f,0.f};
        #pragma unroll
        for (int kk = 0; kk < 8; kk += 2) {
            v8h a0 = *(const v8h*)(ab + 32 * kk);
            v8h a1 = *(const v8h*)(ab + 32 * (kk + 1));
            C0a = __builtin_amdgcn_mfma_f32_16x16x32_f16(a0, wF0[kk], C0a, 0, 0, 0);
            C1a = __builtin_amdgcn_mfma_f32_16x16x32_f16(a0, wF1[kk], C1a, 0, 0, 0);
            C0b = __builtin_amdgcn_mfma_f32_16x16x32_f16(a1, wF0[kk + 1], C0b, 0, 0, 0);
            C1b = __builtin_amdgcn_mfma_f32_16x16x32_f16(a1, wF1[kk + 1], C1b, 0, 0, 0);
        }
        v4f C0s = C0a + C0b, C1s = C1a + C1b;
        z10 = C0s[0] + b1r0;  P0 = C0s[1];
        z11 = C1s[0] + b1r1;  P1 = C1s[1];
    }
    __syncthreads();   // prologue reads done before iter-0 overwrites buf0

    const float dt = 0.01f, hdt = 0.005f, dt6 = 0.01f / 6.f;
    const float dtdt6 = dt * dt6, hdt2 = hdt * hdt, dthdt = dt * hdt;
    // quad's stage: aq (P coeff), bq (lagged-Y coeff); stage weights
    const float aq  = (quad == 0) ? 0.f : (quad == 3) ? dt : hdt;
    const float bq  = (quad == 2) ? hdt2 : (quad == 3) ? dthdt : 0.f;
    const float wsp = (quad == 0 || quad == 3) ? 1.f : 2.f;
    const float wsq = (quad == 3) ? 0.f : 1.f;

    // lagged Y (step 0: 0 -> dz3 ~ hdt^2*Y1 ~ 2.5e-5, benign)
    float hY0 = 0.f, hY1v = 0.f;   // quad2 lags Y1, quad3 lags Y2
    float S1p0 = 0.f, S23p0 = 0.f, S1p1 = 0.f, S23p1 = 0.f, cn = 99.f;

    #pragma unroll 1
    for (int n = 0; n < NSTEPS; ++n) {
        const int bo = (n & 1) * (4 * US);   // double-buffer offset

        // ---- quad-assigned stage z (both comps), lagged Y in bq term ----
        float zA0 = z10 + aq * P0 - bq * hY0;
        float zA1 = z11 + aq * P1 - bq * hY1v;
        float e0 = __expf(2.f * zA0), e1 = __expf(2.f * zA1);
        float hh0 = 1.f - 2.f / (e0 + 1.f), hh1 = 1.f - 2.f / (e1 + 1.f);
        float u0 = (1.f - hh0 * hh0) * w2r0, u1 = (1.f - hh1 * hh1) * w2r1;
        ubuf[bo + quad * US + c0] = (_Float16)u0;   // full-exec writes
        ubuf[bo + quad * US + c1] = (_Float16)u1;
        __syncthreads();   // the ONLY barrier per step

        // ---- ONE MFMA block: Y1..Y4 for both comps, all in-lane ----
        float Y10, Y20, Y30, Y40, Y11, Y21, Y31, Y41;
        {
            const _Float16* ab = ubuf + bo + sel + 8 * quad;
            v4f C0a = {0.f,0.f,0.f,0.f}, C0b = {0.f,0.f,0.f,0.f};
            v4f C1a = {0.f,0.f,0.f,0.f}, C1b = {0.f,0.f,0.f,0.f};
            #pragma unroll
            for (int kk = 0; kk < 8; kk += 2) {
                v8h a0 = *(const v8h*)(ab + 32 * kk);
                v8h a1 = *(const v8h*)(ab + 32 * (kk + 1));
                MFMA_AV(C0a, a0, wM0[kk]);
                MFMA_AV(C1a, a0, wM1[kk]);
                MFMA_AV(C0b, a1, wM0[kk + 1]);
                MFMA_AV(C1b, a1, wM1[kk + 1]);
            }
            v4f C0s = C0a + C0b, C1s = C1a + C1b;
            Y10 = C0s[0]; Y20 = C0s[1]; Y30 = C0s[2]; Y40 = C0s[3];
            Y11 = C1s[0]; Y21 = C1s[1]; Y31 = C1s[2]; Y41 = C1s[3];
        }
        // no second barrier: next iter writes the OTHER buffer; any wave
        // reaching those writes has passed this iter's barrier, which
        // implies all waves finished the previous buffer's reads.

        // ---- step update (exact current Ys); refresh lagged Y ----
        z10 = z10 + dt * P0 - dtdt6 * (Y10 + Y20 + Y30);
        P0  = P0 - dt6 * (Y10 + 2.f * Y20 + 2.f * Y30 + Y40);
        z11 = z11 + dt * P1 - dtdt6 * (Y11 + Y21 + Y31);
        P1  = P1 - dt6 * (Y11 + 2.f * Y21 + 2.f * Y31 + Y41);
        hY0  = (quad == 3) ? Y20 : Y10;
        hY1v = (quad == 3) ? Y21 : Y11;

        // ---- per-lane S partials (own stage's u, both comps) ----
        S1p0 += wsp * u0;  S23p0 += cn * (wsp * u0) + wsq * u0;
        S1p1 += wsp * u1;  S23p1 += cn * (wsp * u1) + wsq * u1;
        cn -= 1.f;
    }

    // ---- epilogue: reduce S over the 4 quads; buf0 rows {S1, S23, 0, 0} ----
    S1p0  += __shfl_xor(S1p0, 16, 64);   S1p0  += __shfl_xor(S1p0, 32, 64);
    S23p0 += __shfl_xor(S23p0, 16, 64);  S23p0 += __shfl_xor(S23p0, 32, 64);
    S1p1  += __shfl_xor(S1p1, 16, 64);   S1p1  += __shfl_xor(S1p1, 32, 64);
    S23p1 += __shfl_xor(S23p1, 16, 64);  S23p1 += __shfl_xor(S23p1, 32, 64);
    __syncthreads();
    if (quad == 0) {
        ubuf[c0] = (_Float16)S1p0;       ubuf[c1] = (_Float16)S1p1;
        ubuf[US + c0] = (_Float16)S23p0; ubuf[US + c1] = (_Float16)S23p1;
        ubuf[2 * US + c0] = (_Float16)0.f;  ubuf[2 * US + c1] = (_Float16)0.f;
        ubuf[3 * US + c0] = (_Float16)0.f;  ubuf[3 * US + c1] = (_Float16)0.f;
    }
    __syncthreads();
    // wBt[kk][j] = W[c][32kk+8quad+j] = wldsT[(32kk+8quad+j)*WS + c]
    v8h wBt0[8], wBt1[8];
    #pragma unroll
    for (int kk = 0; kk < 8; ++kk)
        #pragma unroll
        for (int j = 0; j < 8; ++j) {
            wBt0[kk][j] = wldsT[(32 * kk + 8 * quad + j) * WS + c0];
            wBt1[kk][j] = wldsT[(32 * kk + 8 * quad + j) * WS + c1];
        }
    float D10, D20, D11, D21;
    {
        const _Float16* ab = ubuf + sel + 8 * quad;
        v4f C0a = {0.f,0.f,0.f,0.f}, C0b = {0.f,0.f,0.f,0.f};
        v4f C1a = {0.f,0.f,0.f,0.f}, C1b = {0.f,0.f,0.f,0.f};
        #pragma unroll
        for (int kk = 0; kk < 8; kk += 2) {
            v8h a0 = *(const v8h*)(ab + 32 * kk);
            v8h a1 = *(const v8h*)(ab + 32 * (kk + 1));
            C0a = __builtin_amdgcn_mfma_f32_16x16x32_f16(a0, wBt0[kk], C0a, 0, 0, 0);
            C1a = __builtin_amdgcn_mfma_f32_16x16x32_f16(a0, wBt1[kk], C1a, 0, 0, 0);
            C0b = __builtin_amdgcn_mfma_f32_16x16x32_f16(a1, wBt0[kk + 1], C0b, 0, 0, 0);
            C1b = __builtin_amdgcn_mfma_f32_16x16x32_f16(a1, wBt1[kk + 1], C1b, 0, 0, 0);
        }
        v4f C0s = C0a + C0b, C1s = C1a + C1b;
        D10 = C0s[0];  D20 = C0s[1];
        D11 = C1s[0];  D21 = C1s[1];
    }
    const float dt6e = 0.01f / 6.f, dtdt6e = 0.01f * dt6e;
    float pT0 = p0o0 - dt6e * D10;
    float qT0 = q0o0 + 0.01f * (float)NSTEPS * p0o0 - dtdt6e * D20;
    float pT1 = p0o1 - dt6e * D11;
    float qT1 = q0o1 + 0.01f * (float)NSTEPS * p0o1 - dtdt6e * D21;

    if (quad == 0) {
        ((float2*)(out + (size_t)blk * 512))[c0] = make_float2(qT0, pT0);
        ((float2*)(out + (size_t)blk * 512))[c1] = make_float2(qT1, pT1);
    }
}

extern "C" void kernel_launch(void* const* d_in, const int* in_sizes, int n_in,
                              void* d_out, int out_size, void* d_ws, size_t ws_size,
                              hipStream_t stream) {
    const float* x0 = (const float*)d_in[0];
    const float* W1 = (const float*)d_in[1];
    const float* b1 = (const float*)d_in[2];
    const float* W2 = (const float*)d_in[3];
    // d_in[4] = b2: constant offset, no effect on the gradient/dynamics.
    float* out = (float*)d_out;
    hipLaunchKernelGGL(ham_kernel, dim3(256), dim3(512), 0, stream,
                       x0, W1, b1, W2, out);
}